// Round 18
// baseline (120.430 us; speedup 1.0000x reference)
//
#include <hip/hip_runtime.h>
#include <hip/hip_bf16.h>
#include <hip/hip_fp16.h>

typedef _Float16 h8 __attribute__((ext_vector_type(8)));
typedef _Float16 h2 __attribute__((ext_vector_type(2)));
typedef float f4 __attribute__((ext_vector_type(4)));
typedef float f16v __attribute__((ext_vector_type(16)));
typedef int i2v __attribute__((ext_vector_type(2)));

#define NH 8
#define DH 64
#define NPIX 1024
#define CIN 64
#define NBH 64
// 512 (ref scale) * log2(e): logits come out in base-2 units
#define QSCALE (512.0f * 1.44269504f)
#define LOSCALE 2048.0f
#define INV_LOSCALE (1.0f / 2048.0f)
#define DTHR 12.0f

__device__ __forceinline__ float fexp2(float x) {
#if __has_builtin(__builtin_amdgcn_exp2f)
  return __builtin_amdgcn_exp2f(x);
#else
  return exp2f(x);
#endif
}

__device__ __forceinline__ unsigned pk16(float a, float b) {
  auto r = __builtin_amdgcn_cvt_pkrtz(a, b);   // __fp16 ext_vector(2)
  union { decltype(r) h; unsigned u; } x;
  x.h = r;
  return x.u;
}

// ---------------- QKV projection via compensated fp16 MFMA ----------------
// Q/K written row-major [bh][p][d] (hi+lo); V written TRANSPOSED [bh][d][p].
__global__ __launch_bounds__(256) void qkv_mfma(
    const float* __restrict__ x, const float* __restrict__ wqkv,
    _Float16* __restrict__ Qh, _Float16* __restrict__ Ql,
    _Float16* __restrict__ Kh, _Float16* __restrict__ Kl,
    _Float16* __restrict__ Vt) {
  __shared__ __align__(16) char QS[49152];
  char* Wh = QS;
  char* Wl = QS + 16384;
  char* Xh = QS + 32768;
  char* Xl = QS + 40960;
  char* Thi = QS;              // epilogue reuse: [64 p][128 o] f16 = 16KB
  char* Tlo = QS + 16384;

  const int tid = threadIdx.x;
  const int lane = tid & 63;
  const int w = tid >> 6;
  const int c = lane & 15;
  const int g = lane >> 4;
  const int o0 = blockIdx.x * 128;
  const int p0 = blockIdx.y * 64;
  const int b = blockIdx.z;

  #pragma unroll
  for (int it = 0; it < 4; ++it) {
    int task = tid + it * 256;
    int oct = task & 7, o = task >> 3;
    const f4* wr = (const f4*)(wqkv + (size_t)(o0 + o) * CIN + oct * 8);
    f4 wa = wr[0], wb = wr[1];
    h8 hi, lo;
    #pragma unroll
    for (int e = 0; e < 8; ++e) {
      float v = e < 4 ? wa[e] : wb[e - 4];
      _Float16 h = (_Float16)v;
      hi[e] = h;
      lo[e] = (_Float16)((v - (float)h) * LOSCALE);
    }
    int byo = o * 128 + ((oct ^ (o & 7)) << 4);
    *(h8*)(Wh + byo) = hi;
    *(h8*)(Wl + byo) = lo;
  }
  {
    int kp = tid & 31;      // c-pair: channels 2kp, 2kp+1
    int pgrp = tid >> 5;    // p-octet 0..7
    const float* xr0 = x + ((size_t)b * CIN + 2 * kp) * NPIX + p0 + pgrp * 8;
    const float* xr1 = xr0 + NPIX;
    f4 a0 = *(const f4*)xr0, a1 = *(const f4*)(xr0 + 4);
    f4 b0 = *(const f4*)xr1, b1 = *(const f4*)(xr1 + 4);
    int oct = kp >> 2;
    int slot4 = (kp & 3) * 4;
    #pragma unroll
    for (int e = 0; e < 8; ++e) {
      float v0 = e < 4 ? a0[e] : a1[e - 4];
      float v1 = e < 4 ? b0[e] : b1[e - 4];
      _Float16 h0 = (_Float16)v0, h1 = (_Float16)v1;
      float l0f = (v0 - (float)h0) * LOSCALE;
      float l1f = (v1 - (float)h1) * LOSCALE;
      int p = pgrp * 8 + e;
      int byo = p * 128 + ((oct ^ (p & 7)) << 4) + slot4;
      union { h2 h; unsigned u; } uh, ul;
      uh.h[0] = h0; uh.h[1] = h1;
      ul.h[0] = (_Float16)l0f; ul.h[1] = (_Float16)l1f;
      *(unsigned*)(Xh + byo) = uh.u;
      *(unsigned*)(Xl + byo) = ul.u;
    }
  }
  __syncthreads();

  f4 zf = {0.f, 0.f, 0.f, 0.f};
  f4 acc[2][4], cor[2][4];
  #pragma unroll
  for (int oi = 0; oi < 2; ++oi)
    #pragma unroll
    for (int pi = 0; pi < 4; ++pi) { acc[oi][pi] = zf; cor[oi][pi] = zf; }

  const int ob = w * 32;
  #pragma unroll
  for (int kh = 0; kh < 2; ++kh) {
    h8 ah[2], al[2], bh[4], bl[4];
    #pragma unroll
    for (int oi = 0; oi < 2; ++oi) {
      int orow = ob + ((c >> 2) << 3) + (c & 3) + oi * 4;
      int ch = (((kh * 4 + g) ^ (orow & 7)) << 4);
      ah[oi] = *(const h8*)(Wh + orow * 128 + ch);
      al[oi] = *(const h8*)(Wl + orow * 128 + ch);
    }
    #pragma unroll
    for (int pi = 0; pi < 4; ++pi) {
      int prow = pi * 16 + c;
      int ch = (((kh * 4 + g) ^ (prow & 7)) << 4);
      bh[pi] = *(const h8*)(Xh + prow * 128 + ch);
      bl[pi] = *(const h8*)(Xl + prow * 128 + ch);
    }
    __builtin_amdgcn_s_setprio(1);
    #pragma unroll
    for (int oi = 0; oi < 2; ++oi)
      #pragma unroll
      for (int pi = 0; pi < 4; ++pi) {
        acc[oi][pi] = __builtin_amdgcn_mfma_f32_16x16x32_f16(ah[oi], bh[pi], acc[oi][pi], 0, 0, 0);
        cor[oi][pi] = __builtin_amdgcn_mfma_f32_16x16x32_f16(ah[oi], bl[pi], cor[oi][pi], 0, 0, 0);
        cor[oi][pi] = __builtin_amdgcn_mfma_f32_16x16x32_f16(al[oi], bh[pi], cor[oi][pi], 0, 0, 0);
      }
    __builtin_amdgcn_s_setprio(0);
  }

  const int part = o0 >> 9;
  const float scl = part == 0 ? QSCALE : 1.0f;
  _Float16* dsth = part == 0 ? Qh : (part == 1 ? Kh : Vt);
  _Float16* dstl = part == 0 ? Ql : (part == 1 ? Kl : nullptr);

  __syncthreads();   // all LDS operand reads done; reuse QS for output tile
  {
    const int chunk = 4 * w + g;
    #pragma unroll
    for (int pi = 0; pi < 4; ++pi) {
      int p = pi * 16 + c;
      h8 hv, lv;
      #pragma unroll
      for (int oi = 0; oi < 2; ++oi)
        #pragma unroll
        for (int reg = 0; reg < 4; ++reg) {
          float v = (acc[oi][pi][reg] + cor[oi][pi][reg] * INV_LOSCALE) * scl;
          _Float16 hh = (_Float16)v;
          hv[oi * 4 + reg] = hh;
          lv[oi * 4 + reg] = (_Float16)(v - (float)hh);   // UNSCALED residual
        }
      int byo = p * 256 + ((chunk ^ (p & 15)) << 4);
      *(h8*)(Thi + byo) = hv;
      if (dstl) *(h8*)(Tlo + byo) = lv;
    }
  }
  __syncthreads();
  if (part != 2) {
    // coalesced row stores [bh][p][d]
    #pragma unroll
    for (int it = 0; it < 4; ++it) {
      int task = tid + it * 256;
      int p = task >> 4;
      int ck = task & 15;
      int byo = p * 256 + ((ck ^ (p & 15)) << 4);
      int o = o0 + ck * 8;
      int h = (o >> 6) & 7;
      int d = o & 63;
      size_t off = (((size_t)(b * NH + h)) * NPIX + p0 + p) * DH + d;
      h8 v = *(const h8*)(Thi + byo);
      *(h8*)(dsth + off) = v;
      if (dstl) {
        h8 v2 = *(const h8*)(Tlo + byo);
        *(h8*)(dstl + off) = v2;
      }
    }
  } else {
    // V transposed stores: Vt[(bh*64 + d)][p0 + 8*po .. +8]
    #pragma unroll
    for (int it = 0; it < 4; ++it) {
      int task = tid + it * 256;
      int o = task >> 3;       // o-local 0..127
      int po = task & 7;       // p-octet
      h8 vv;
      #pragma unroll
      for (int e = 0; e < 8; ++e) {
        int p = po * 8 + e;
        vv[e] = *(const _Float16*)(Thi + p * 256 + (((o >> 3) ^ (p & 15)) << 4) + (o & 7) * 2);
      }
      int oabs = o0 + o;
      int h = (oabs >> 6) & 7;
      int d = oabs & 63;
      size_t off = (((size_t)(b * NH + h)) * DH + d) * NPIX + p0 + po * 8;
      *(h8*)(Vt + off) = vv;
    }
  }
}

// ---------------- fused MFMA attention: barrier-free main loop ------------
// Wave w owns rows i = w*32 + (lane&31); k/j slot = lane>>5.
// All MFMA A-operands load DIRECTLY from global (K/Kl rows, Vt rows);
// B-operands are registers (Q preloaded, P via cvt_pk+permlane32_swap).
// LDS (40KB): prologue rel (0..16K) + LWT (16..32K) -> OT epilogue (0..32K);
// LHc persistent 32K..40K. Main loop: zero LDS writes, zero barriers.
__global__ __launch_bounds__(256) void attn_mfma(
    const _Float16* __restrict__ Qh, const _Float16* __restrict__ Ql,
    const _Float16* __restrict__ Kh, const _Float16* __restrict__ Kl,
    const _Float16* __restrict__ Vt,
    const float* __restrict__ rel_h, const float* __restrict__ rel_w,
    float* __restrict__ out) {
  __shared__ __align__(16) char SMem[40960];
  _Float16* LHc = (_Float16*)(SMem + 32768);  // [16 t][128 rows][2] fp16
  _Float16* LWT = (_Float16*)(SMem + 16384);  // prologue temp [128][64]
  float* OT = (float*)SMem;                   // epilogue [64][128] f32

  const int tid = threadIdx.x;
  const int lane = tid & 63;
  const int w = tid >> 6;
  const int c = lane & 15;
  const int g = lane >> 4;
  const int il = lane & 31;
  const int hi = lane >> 5;
  const int bx = blockIdx.x;
  const int bh = ((bx & 7) << 3) | ((bx >> 3) & 7);
  const int i0 = (bx >> 6) << 7;

  const _Float16* Qhg = Qh + (size_t)bh * NPIX * DH;
  const _Float16* Qlg = Ql + (size_t)bh * NPIX * DH;
  const h8* KH8 = (const h8*)(Kh + (size_t)bh * NPIX * DH);
  const h8* KL8 = (const h8*)(Kl + (size_t)bh * NPIX * DH);
  const h8* VT8 = (const h8*)(Vt + (size_t)bh * DH * NPIX);

  // prologue Q fragments (16x16 B operand)
  const h8* Qr0h = (const h8*)(Qhg + (size_t)(i0 + w * 32 + c) * DH);
  const h8* Qr0l = (const h8*)(Qlg + (size_t)(i0 + w * 32 + c) * DH);
  const h8* Qr1h = (const h8*)(Qhg + (size_t)(i0 + w * 32 + 16 + c) * DH);
  const h8* Qr1l = (const h8*)(Qlg + (size_t)(i0 + w * 32 + 16 + c) * DH);
  h8 q0h[2] = {Qr0h[g], Qr0h[4 + g]};
  h8 q0l[2] = {Qr0l[g], Qr0l[4 + g]};
  h8 q1h[2] = {Qr1h[g], Qr1h[4 + g]};
  h8 q1l[2] = {Qr1l[g], Qr1l[4 + g]};

  // ---- stage rel tables: rel_h @0, rel_w @8K ----
  #pragma unroll
  for (int it = 0; it < 2; ++it) {
    int task = tid + it * 256;
    int oct = task & 7, s = task >> 3;
    int ss = s < 63 ? s : 62;
    const float* sh = rel_h + (size_t)ss * DH + oct * 8;
    const float* sw = rel_w + (size_t)ss * DH + oct * 8;
    h8 hh, ww;
    #pragma unroll
    for (int e = 0; e < 8; ++e) {
      hh[e] = (_Float16)sh[e];
      ww[e] = (_Float16)sw[e];
    }
    int byo = s * 128 + ((oct ^ (s & 7)) << 4);
    *(h8*)(SMem + byo) = hh;
    *(h8*)(SMem + 8192 + byo) = ww;
  }
  __syncthreads();

  // ---- lh/lw tables via swapped 16x16 MFMA (lo folded into same acc) ----
  const int yi = (i0 + w * 32) >> 5;
  f4 zf = {0.f, 0.f, 0.f, 0.f};
  #pragma unroll
  for (int rs = 0; rs < 2; ++rs) {
    f4 lhD[4], lwD[4];
    #pragma unroll
    for (int st = 0; st < 4; ++st) { lhD[st] = zf; lwD[st] = zf; }
    #pragma unroll
    for (int kh = 0; kh < 2; ++kh) {
      h8 bq = rs ? q1h[kh] : q0h[kh];
      h8 bl = rs ? q1l[kh] : q0l[kh];
      #pragma unroll
      for (int st = 0; st < 4; ++st) {
        int srow = st * 16 + c;
        int chb = srow * 128 + (((kh * 4 + g) ^ (srow & 7)) << 4);
        h8 ra = *(const h8*)(SMem + chb);
        h8 wa = *(const h8*)(SMem + 8192 + chb);
        lhD[st] = __builtin_amdgcn_mfma_f32_16x16x32_f16(ra, bq, lhD[st], 0, 0, 0);
        lhD[st] = __builtin_amdgcn_mfma_f32_16x16x32_f16(ra, bl, lhD[st], 0, 0, 0);
        lwD[st] = __builtin_amdgcn_mfma_f32_16x16x32_f16(wa, bq, lwD[st], 0, 0, 0);
        lwD[st] = __builtin_amdgcn_mfma_f32_16x16x32_f16(wa, bl, lwD[st], 0, 0, 0);
      }
    }
    int lrow = w * 32 + rs * 16 + c;
    #pragma unroll
    for (int st = 0; st < 4; ++st)
      #pragma unroll
      for (int reg = 0; reg < 4; ++reg) {
        int s = st * 16 + 4 * g + reg;
        int k = s - 31 + yi;
        if (k >= 0 && k < 32)
          LHc[(k >> 1) * 256 + lrow * 2 + (k & 1)] = (_Float16)lhD[st][reg];
        LWT[lrow * 64 + s] = (_Float16)lwD[st][reg];
      }
  }
  __syncthreads();

  // lwp[reg]: lw[i][31 + jl(reg) - il], jl = (reg&3)+8*(reg>>2)+4*hi
  float lwp[16];
  {
    int r = w * 32 + il;
    #pragma unroll
    for (int reg = 0; reg < 16; ++reg) {
      int jl = (reg & 3) + 8 * (reg >> 2) + 4 * hi;
      lwp[reg] = (float)LWT[r * 64 + 31 + jl - il];
    }
  }
  // main-loop Q fragments (32x32 B operand: col = il, k-slot = hi)
  const h8* Qmh = (const h8*)(Qhg + (size_t)(i0 + w * 32 + il) * DH);
  const h8* Qml = (const h8*)(Qlg + (size_t)(i0 + w * 32 + il) * DH);
  h8 qmh[4], qml[4];
  #pragma unroll
  for (int kb = 0; kb < 4; ++kb) {
    qmh[kb] = Qmh[2 * kb + hi];
    qml[kb] = Qml[2 * kb + hi];
  }
  __syncthreads();   // everyone past rel/LWT reads (OT will overlay them)

  float m_s = -1e30f, lp = 0.f;
  f16v O0, O1;
  #pragma unroll
  for (int e = 0; e < 16; ++e) { O0[e] = 0.f; O1[e] = 0.f; }

  // per-lane h8-indices
  const int kidx0 = il * 8 + hi;            // K rows il   (h8 units)
  const int kidx1 = (32 + il) * 8 + hi;     // K rows 32+il
  const int vidx0 = il * 128 + hi;          // Vt row d=il
  const int vidx1 = (32 + il) * 128 + hi;   // Vt row d=32+il
  const int lhr = (w * 32 + il) * 2;

  #pragma unroll 1
  for (int t = 0; t < 16; ++t) {
    const int kt = t * 512;                 // tile offset in h8 units (64 rows * 8)
    const int vt_ = t * 8;                  // tile offset in Vt h8 units

    // ---- K fragments direct from global (row-contiguous 16B each) ----
    h8 a0h[4], a0l[4], a1h[4], a1l[4];
    #pragma unroll
    for (int kb = 0; kb < 4; ++kb) {
      a0h[kb] = KH8[kt + kidx0 + 2 * kb];
      a0l[kb] = KL8[kt + kidx0 + 2 * kb];
      a1h[kb] = KH8[kt + kidx1 + 2 * kb];
      a1l[kb] = KL8[kt + kidx1 + 2 * kb];
    }

    // ---- QK^T swapped 32x32x16 ----
    f16v S0, S1;
    #pragma unroll
    for (int e = 0; e < 16; ++e) { S0[e] = 0.f; S1[e] = 0.f; }
    #pragma unroll
    for (int kb = 0; kb < 4; ++kb) {
      __builtin_amdgcn_s_setprio(1);
      S0 = __builtin_amdgcn_mfma_f32_32x32x16_f16(a0h[kb], qmh[kb], S0, 0, 0, 0);
      S0 = __builtin_amdgcn_mfma_f32_32x32x16_f16(a0l[kb], qmh[kb], S0, 0, 0, 0);
      S0 = __builtin_amdgcn_mfma_f32_32x32x16_f16(a0h[kb], qml[kb], S0, 0, 0, 0);
      S1 = __builtin_amdgcn_mfma_f32_32x32x16_f16(a1h[kb], qmh[kb], S1, 0, 0, 0);
      S1 = __builtin_amdgcn_mfma_f32_32x32x16_f16(a1l[kb], qmh[kb], S1, 0, 0, 0);
      S1 = __builtin_amdgcn_mfma_f32_32x32x16_f16(a1h[kb], qml[kb], S1, 0, 0, 0);
      __builtin_amdgcn_s_setprio(0);
    }

    // ---- V fragments direct from global (latency hides under finish) ----
    h8 av0[4], av1[4];
    #pragma unroll
    for (int jkb = 0; jkb < 4; ++jkb) {
      av0[jkb] = VT8[vidx0 + vt_ + 2 * jkb];
      av1[jkb] = VT8[vidx1 + vt_ + 2 * jkb];
    }

    // ---- finish: bias + speculative softmax + in-register P fragments ----
    h8 fr[4];
    {
      h2 lhu = *(const h2*)(LHc + t * 256 + lhr);
      float lh0 = (float)lhu[0], lh1 = (float)lhu[1];
      #pragma unroll
      for (int reg = 0; reg < 16; ++reg) {
        S0[reg] += lwp[reg] + lh0;
        S1[reg] += lwp[reg] + lh1;
      }
      // speculative exp2 with the OLD max — overlaps the max-tree below
      float pv0[16], pv1[16];
      #pragma unroll
      for (int e = 0; e < 16; ++e) {
        pv0[e] = fexp2(S0[e] - m_s);
        pv1[e] = fexp2(S1[e] - m_s);
      }
      float v8[8];
      #pragma unroll
      for (int e = 0; e < 8; ++e)
        v8[e] = fmaxf(fmaxf(S0[e], S0[e + 8]), fmaxf(S1[e], S1[e + 8]));
      float w0 = fmaxf(fmaxf(v8[0], v8[1]), fmaxf(v8[2], v8[3]));
      float w1 = fmaxf(fmaxf(v8[4], v8[5]), fmaxf(v8[6], v8[7]));
      float mx = fmaxf(w0, w1);
      mx = fmaxf(mx, __shfl_xor(mx, 32, 64));
      bool sk = mx <= m_s + DTHR;      // T13 defer-max: skip is common
      if (!__all(sk)) {                // rare: recompute with new max
        float mn = fmaxf(m_s, mx);
        float corr = fexp2(m_s - mn);
        m_s = mn;
        lp *= corr;
        #pragma unroll
        for (int e = 0; e < 16; ++e) { O0[e] *= corr; O1[e] *= corr; }
        #pragma unroll
        for (int e = 0; e < 16; ++e) {
          pv0[e] = fexp2(S0[e] - m_s);
          pv1[e] = fexp2(S1[e] - m_s);
        }
      }
      f4 ps = zf;
      #pragma unroll
      for (int e = 0; e < 16; e += 4) {
        ps[0] += pv0[e] + pv1[e];
        ps[1] += pv0[e + 1] + pv1[e + 1];
        ps[2] += pv0[e + 2] + pv1[e + 2];
        ps[3] += pv0[e + 3] + pv1[e + 3];
      }
      lp += (ps[0] + ps[1]) + (ps[2] + ps[3]);
      // T12: build PV B-operand fragments in-register
      #pragma unroll
      for (int jkb = 0; jkb < 4; ++jkb) {
        const float* pv = (jkb < 2) ? pv0 : pv1;
        int base = (jkb & 1) * 8;
        unsigned x01 = pk16(pv[base + 0], pv[base + 1]);
        unsigned x23 = pk16(pv[base + 2], pv[base + 3]);
        unsigned y01 = pk16(pv[base + 4], pv[base + 5]);
        unsigned y23 = pk16(pv[base + 6], pv[base + 7]);
        i2v r1 = __builtin_amdgcn_permlane32_swap((int)x01, (int)y01, false, false);
        i2v r2 = __builtin_amdgcn_permlane32_swap((int)x23, (int)y23, false, false);
        union { unsigned u[4]; h8 h; } fu;
        fu.u[0] = (unsigned)r1[0];
        fu.u[1] = (unsigned)r2[0];
        fu.u[2] = (unsigned)r1[1];
        fu.u[3] = (unsigned)r2[1];
        fr[jkb] = fu.h;
      }
    }

    // ---- PV swapped 32x32x16: A=Vt (global regs), B=P (registers) ----
    #pragma unroll
    for (int jkb = 0; jkb < 4; ++jkb) {
      __builtin_amdgcn_s_setprio(1);
      O0 = __builtin_amdgcn_mfma_f32_32x32x16_f16(av0[jkb], fr[jkb], O0, 0, 0, 0);
      O1 = __builtin_amdgcn_mfma_f32_32x32x16_f16(av1[jkb], fr[jkb], O1, 0, 0, 0);
      __builtin_amdgcn_s_setprio(0);
    }
  }

  // ---- epilogue: reduce l across hi, normalize, transpose, store ----
  float lt = lp + __shfl_xor(lp, 32, 64);
  float rr = __builtin_amdgcn_rcpf(lt);
  {
    int r = w * 32 + il;
    #pragma unroll
    for (int reg = 0; reg < 16; ++reg) {
      int dl = (reg & 3) + 8 * (reg >> 2) + 4 * hi;
      int d0 = dl;
      int d1 = 32 + dl;
      OT[d0 * 128 + (r ^ ((d0 & 7) << 3))] = O0[reg] * rr;
      OT[d1 * 128 + (r ^ ((d1 & 7) << 3))] = O1[reg] * rr;
    }
  }
  __syncthreads();
  #pragma unroll
  for (int it = 0; it < 8; ++it) {
    int task = tid + it * 256;
    int rq = task & 31, d = task >> 5;
    f4 vv = *(const f4*)&OT[d * 128 + ((rq * 4) ^ ((d & 7) << 3))];
    *(f4*)(out + (((size_t)bh * 64 + d) << 10) + i0 + rq * 4) = vv;
  }
}

extern "C" void kernel_launch(void* const* d_in, const int* in_sizes, int n_in,
                              void* d_out, int out_size, void* d_ws, size_t ws_size,
                              hipStream_t stream) {
  const float* x  = (const float*)d_in[0];
  const float* wq = (const float*)d_in[1];
  const float* rh = (const float*)d_in[2];
  const float* rw = (const float*)d_in[3];
  float* out = (float*)d_out;

  const size_t sz = (size_t)NBH * NPIX * DH;
  _Float16* Qh = (_Float16*)d_ws;
  _Float16* Ql = Qh + sz;
  _Float16* Kh = Ql + sz;
  _Float16* Kl = Kh + sz;
  _Float16* Vt = Kl + sz;

  qkv_mfma<<<dim3(12, 16, 8), 256, 0, stream>>>(x, wq, Qh, Ql, Kh, Kl, Vt);
  attn_mfma<<<dim3(512), 256, 0, stream>>>(Qh, Ql, Kh, Kl, Vt, rh, rw, out);
}